// Round 14
// baseline (1244.910 us; speedup 1.0000x reference)
//
#include <hip/hip_runtime.h>
#include <math.h>

#define B_SZ 8192
#define H_SZ 2048
#define I_SZ 1024
#define O_SZ 512

// ======== f32 math mirroring numpy float32 semantics ========
// Config (r14 = r13 numerics, faster eta GEMM): eta matmul = f64-accumulated
// dot rounded to f32 (PROVEN r13); biases f32 in np order; sqrt CR;
// tan/atan/tanh/atanh ocml. Accumulation order unchanged (strict ascending k,
// f64 FMA chain) -> eta bit-identical to r13.

__device__ __forceinline__ float signf_(float x) {
    return (x > 0.f) ? 1.f : ((x < 0.f) ? -1.f : 0.f);
}

__device__ __forceinline__ float next_spike_f32(float v, float eta) {
#pragma clang fp contract(off)
    const float EPSf = 1e-6f;
    const float HEPSf = (float)(0.5 * 1e-6);
    const float T_INF = 10000.f;
    const float PI_F = (float)3.14159265358979323846;
    float ae = fabsf(eta) + EPSf;
    float se = (float)sqrt((double)ae);        // correctly-rounded f32 sqrt
    float s1 = signf_(v);
    float t1 = EPSf * s1;
    float va = v + t1;
    float vpe = v + EPSf;
    float s2 = signf_(vpe);
    float t2 = HEPSf * s2;
    float vs = va + t2;                        // ((v + e*s1) + he*s2)
    if (eta == 0.f) {
        if (v > 0.f) return 1.f / vs;
        return T_INF;
    }
    if (eta < 0.f) {
        if (v > se) {
            float r = se / vs;
            const float lo = (float)(-1.0 + 1e-6);
            const float hi = (float)(1.0 - 1e-6);
            r = fminf(fmaxf(r, lo), hi);
            float at = atanhf(r);              // ocml
            return at / se;
        }
        return T_INF;
    }
    float q = se / vs;
    float a = atanf(q);                        // ocml
    if (a < 0.f) a = a + PI_F;                 // np.mod(a, pi) for |a| < pi
    return a / se;
}

__device__ __forceinline__ float update_pot_f32(float v, float eta, float dt) {
#pragma clang fp contract(off)
    const float EPSf = 1e-6f;
    float ae = fabsf(eta) + EPSf;
    float se = (float)sqrt((double)ae);
    float r;
    if (eta == 0.f) {
        float t1 = dt * v;
        float den = 1.f - t1;
        r = v / den;
    } else if (eta < 0.f) {
        float x = se * dt;
        float th = tanhf(x);                   // ocml
        float t1 = se * th;
        float num = v - t1;
        float t2 = th * v;
        float t3 = t2 / se;
        float den = 1.f - t3;
        r = num / den;
    } else {
        float x = se * dt;
        float ta = tanf(x);                    // ocml
        float t1 = se * ta;
        float num = v + t1;
        float t2 = ta * v;
        float t3 = t2 / se;
        float den = 1.f - t3;
        r = num / den;
    }
    const float HI = (float)1e25;
    r = r < -HI ? -HI : (r > HI ? HI : r);     // NaN passes through, like np.clip
    return r;
}

// ---------------- transpose (32x32 LDS tiles) ----------------

__global__ __launch_bounds__(256) void transpose_kernel(const float* __restrict__ in,
                                                        float* __restrict__ out,
                                                        int R, int C) {
    __shared__ float tile[32][33];
    int bx = blockIdx.x * 32;
    int by = blockIdx.y * 32;
    int tx = threadIdx.x;
    int ty = threadIdx.y;
#pragma unroll
    for (int i = ty; i < 32; i += 8)
        tile[i][tx] = in[(size_t)(by + i) * C + bx + tx];
    __syncthreads();
#pragma unroll
    for (int i = ty; i < 32; i += 8)
        out[(size_t)(bx + i) * R + by + tx] = tile[tx][i];
}

// ---------------- eta GEMM: f64-accumulated dot, rounded to f32 ----------------
// Optimized r14: f64 LDS staging (no inner-loop cvt), vector LDS reads,
// conflict-free B mapping (cols {tx,tx+16,tx+32,tx+48}), GK=32.
// Accumulation order: strict ascending k, sequential f64 FMA (== r13).

#define EK 32

__global__ __launch_bounds__(256, 2) void gemm_eta_f64acc_kernel(
    const float* __restrict__ A,    // [B,I]
    const float* __restrict__ Bm,   // [H,I]
    const float* __restrict__ b_i2h, const float* __restrict__ b_h2h,
    float* __restrict__ C) {
    __shared__ double Ad[EK][66];
    __shared__ double Bd[EK][66];
    const int tid = threadIdx.x;
    const int row0 = blockIdx.y * 64;
    const int col0 = blockIdx.x * 64;
    const int ty = tid >> 4;           // 0..15
    const int tx = tid & 15;           // 0..15
    const int srow = tid >> 2;         // 0..63 (staging row)
    const int sc4 = (tid & 3) << 2;    // 0,4,8,12 (staging k-offset, pass 0)

    double acc[4][4];
#pragma unroll
    for (int i = 0; i < 4; ++i)
#pragma unroll
        for (int j = 0; j < 4; ++j) acc[i][j] = 0.0;

    for (int k0 = 0; k0 < I_SZ; k0 += EK) {
#pragma unroll
        for (int p = 0; p < 2; ++p) {
            int kq = sc4 + p * 16;
            float4 a4 = *reinterpret_cast<const float4*>(
                A + (size_t)(row0 + srow) * I_SZ + k0 + kq);
            float4 b4 = *reinterpret_cast<const float4*>(
                Bm + (size_t)(col0 + srow) * I_SZ + k0 + kq);
            Ad[kq + 0][srow] = (double)a4.x; Ad[kq + 1][srow] = (double)a4.y;
            Ad[kq + 2][srow] = (double)a4.z; Ad[kq + 3][srow] = (double)a4.w;
            Bd[kq + 0][srow] = (double)b4.x; Bd[kq + 1][srow] = (double)b4.y;
            Bd[kq + 2][srow] = (double)b4.z; Bd[kq + 3][srow] = (double)b4.w;
        }
        __syncthreads();
#pragma unroll
        for (int kk = 0; kk < EK; ++kk) {   // strict ascending k
            double2 a01 = *reinterpret_cast<const double2*>(&Ad[kk][ty * 4]);
            double2 a23 = *reinterpret_cast<const double2*>(&Ad[kk][ty * 4 + 2]);
            double b0 = Bd[kk][tx];
            double b1 = Bd[kk][tx + 16];
            double b2 = Bd[kk][tx + 32];
            double b3 = Bd[kk][tx + 48];
            acc[0][0] = fma(a01.x, b0, acc[0][0]);
            acc[0][1] = fma(a01.x, b1, acc[0][1]);
            acc[0][2] = fma(a01.x, b2, acc[0][2]);
            acc[0][3] = fma(a01.x, b3, acc[0][3]);
            acc[1][0] = fma(a01.y, b0, acc[1][0]);
            acc[1][1] = fma(a01.y, b1, acc[1][1]);
            acc[1][2] = fma(a01.y, b2, acc[1][2]);
            acc[1][3] = fma(a01.y, b3, acc[1][3]);
            acc[2][0] = fma(a23.x, b0, acc[2][0]);
            acc[2][1] = fma(a23.x, b1, acc[2][1]);
            acc[2][2] = fma(a23.x, b2, acc[2][2]);
            acc[2][3] = fma(a23.x, b3, acc[2][3]);
            acc[3][0] = fma(a23.y, b0, acc[3][0]);
            acc[3][1] = fma(a23.y, b1, acc[3][1]);
            acc[3][2] = fma(a23.y, b2, acc[3][2]);
            acc[3][3] = fma(a23.y, b3, acc[3][3]);
        }
        __syncthreads();
    }
    {
#pragma clang fp contract(off)
#pragma unroll
        for (int i = 0; i < 4; ++i) {
            int row = row0 + ty * 4 + i;
#pragma unroll
            for (int j = 0; j < 4; ++j) {
                int col = col0 + tx + 16 * j;
                float m32 = (float)acc[i][j];       // f32 of f64-accurate dot
                float s = b_h2h[col] + m32;         // (b_h2h + M)
                s = s + b_i2h[col];                 // + b_i2h
                C[(size_t)row * H_SZ + col] = s;
            }
        }
    }
}

// ---------------- per-row next_spike + min/argmin (all f32) ----------------

__global__ __launch_bounds__(256) void spike_min_kernel(
    const float* __restrict__ v_in, const float* __restrict__ spike,
    const float* __restrict__ eta, const float* __restrict__ t_in,
    const float* __restrict__ syn_p,
    float* __restrict__ t_out, float* __restrict__ mdt_out,
    float* __restrict__ kf_out, int* __restrict__ kidx) {
#pragma clang fp contract(off)
    const int b = blockIdx.x;
    const int tid = threadIdx.x;
    const size_t base = (size_t)b * H_SZ;
    unsigned long long best = 0xFFFFFFFFFFFFFFFFull;
    for (int h = tid; h < H_SZ; h += 256) {
        float vv = v_in[base + h] + spike[base + h];
        float dt = next_spike_f32(vv, eta[base + h]);
        unsigned long long p =
            ((unsigned long long)__float_as_uint(dt) << 32) | (unsigned)h;
        best = (p < best) ? p : best;
    }
#pragma unroll
    for (int off = 1; off < 64; off <<= 1) {
        unsigned long long o = __shfl_xor(best, off);
        best = (o < best) ? o : best;
    }
    __shared__ unsigned long long s[4];
    if ((tid & 63) == 0) s[tid >> 6] = best;
    __syncthreads();
    if (tid == 0) {
        best = s[0];
#pragma unroll
        for (int w = 1; w < 4; ++w)
            if (s[w] < best) best = s[w];
        float mdt = __uint_as_float((unsigned)(best >> 32));
        int k = (int)(best & 0xFFFFFFFFu);
        mdt_out[b] = mdt;
        kf_out[b] = (float)k;
        kidx[b] = k;
        float tt = t_in[b] + mdt;   // np: (t + min_dt) + syn_delay
        tt = tt + (*syn_p);
        t_out[b] = tt;
    }
}

// ---------------- update potential (f32) + recurrent gather ----------------

__global__ __launch_bounds__(256) void update_v_kernel(
    const float* __restrict__ v_in, const float* __restrict__ spike,
    const float* __restrict__ eta, const float* __restrict__ mdt,
    const int* __restrict__ kidx, const float* __restrict__ whhT,
    const float* __restrict__ syn_p, float* __restrict__ v_out) {
#pragma clang fp contract(off)
    size_t i4 = ((size_t)blockIdx.x * 256 + threadIdx.x) * 4;
    if (i4 >= (size_t)B_SZ * H_SZ) return;
    int b = (int)(i4 >> 11);
    int h = (int)(i4 & (H_SZ - 1));
    float dt = mdt[b] + (*syn_p);   // one f32 rounding, matches (min_dt+syn)[:,None]
    int k = kidx[b];
    float4 v4 = *reinterpret_cast<const float4*>(v_in + i4);
    float4 s4 = *reinterpret_cast<const float4*>(spike + i4);
    float4 e4 = *reinterpret_cast<const float4*>(eta + i4);
    float4 w4 = *reinterpret_cast<const float4*>(whhT + (size_t)k * H_SZ + h);
    float4 r;
    r.x = update_pot_f32(v4.x + s4.x, e4.x, dt) + w4.x;
    r.y = update_pot_f32(v4.y + s4.y, e4.y, dt) + w4.y;
    r.z = update_pot_f32(v4.z + s4.z, e4.z, dt) + w4.z;
    r.w = update_pot_f32(v4.w + s4.w, e4.w, dt) + w4.w;
    *reinterpret_cast<float4*>(v_out + i4) = r;
}

// ---------------- output spike gather ----------------

__global__ __launch_bounds__(256) void out_spike_kernel(
    const int* __restrict__ kidx, const float* __restrict__ whoT,
    float* __restrict__ out0) {
    size_t i4 = ((size_t)blockIdx.x * 256 + threadIdx.x) * 4;
    if (i4 >= (size_t)B_SZ * O_SZ) return;
    int b = (int)(i4 >> 9);
    int o = (int)(i4 & (O_SZ - 1));
    int k = kidx[b];
    float4 w = *reinterpret_cast<const float4*>(whoT + (size_t)k * O_SZ + o);
    *reinterpret_cast<float4*>(out0 + i4) = w;
}

// ---------------- f32 tiled GEMM for output_potential (passed every round) ----------------

#define GT 128
#define GK 16

__global__ __launch_bounds__(256, 2) void gemm_f32_clip_kernel(
    const float* __restrict__ A, const float* __restrict__ Bm,
    const float* __restrict__ bias0, float* __restrict__ C,
    int K, const float* __restrict__ vminp, const float* __restrict__ vmaxp) {
    __shared__ float As[GK][GT + 4];
    __shared__ float Bs[GK][GT + 4];
    const int tid = threadIdx.x;
    const int row0 = blockIdx.y * GT;
    const int col0 = blockIdx.x * GT;
    const float vmin = *vminp, vmax = *vmaxp;
    const int lr = tid >> 2;
    const int lc = (tid & 3) << 2;
    const int ty = tid >> 4;
    const int tx = tid & 15;

    float acc[8][8];
#pragma unroll
    for (int i = 0; i < 8; ++i)
#pragma unroll
        for (int j = 0; j < 8; ++j) acc[i][j] = 0.f;

    for (int k0 = 0; k0 < K; k0 += GK) {
#pragma unroll
        for (int half = 0; half < 2; ++half) {
            int r = lr + half * 64;
            float4 a4 = *reinterpret_cast<const float4*>(A + (size_t)(row0 + r) * K + k0 + lc);
            a4.x = fminf(fmaxf(a4.x, vmin), vmax);
            a4.y = fminf(fmaxf(a4.y, vmin), vmax);
            a4.z = fminf(fmaxf(a4.z, vmin), vmax);
            a4.w = fminf(fmaxf(a4.w, vmin), vmax);
            As[lc + 0][r] = a4.x; As[lc + 1][r] = a4.y;
            As[lc + 2][r] = a4.z; As[lc + 3][r] = a4.w;
            float4 b4 = *reinterpret_cast<const float4*>(Bm + (size_t)(col0 + r) * K + k0 + lc);
            Bs[lc + 0][r] = b4.x; Bs[lc + 1][r] = b4.y;
            Bs[lc + 2][r] = b4.z; Bs[lc + 3][r] = b4.w;
        }
        __syncthreads();
#pragma unroll
        for (int kk = 0; kk < GK; ++kk) {
            float a[8], b[8];
#pragma unroll
            for (int i = 0; i < 8; ++i) a[i] = As[kk][ty * 8 + i];
#pragma unroll
            for (int j = 0; j < 8; ++j) b[j] = Bs[kk][tx * 8 + j];
#pragma unroll
            for (int i = 0; i < 8; ++i)
#pragma unroll
                for (int j = 0; j < 8; ++j) acc[i][j] = fmaf(a[i], b[j], acc[i][j]);
        }
        __syncthreads();
    }

    float bb[8];
#pragma unroll
    for (int j = 0; j < 8; ++j) bb[j] = bias0[col0 + tx * 8 + j];
#pragma unroll
    for (int i = 0; i < 8; ++i) {
        int row = row0 + ty * 8 + i;
#pragma unroll
        for (int j = 0; j < 8; j += 4) {
            float4 vstore;
            vstore.x = acc[i][j + 0] + bb[j + 0];
            vstore.y = acc[i][j + 1] + bb[j + 1];
            vstore.z = acc[i][j + 2] + bb[j + 2];
            vstore.w = acc[i][j + 3] + bb[j + 3];
            *reinterpret_cast<float4*>(C + (size_t)row * O_SZ + col0 + tx * 8 + j) = vstore;
        }
    }
}

// ---------------- launch ----------------

extern "C" void kernel_launch(void* const* d_in, const int* in_sizes, int n_in,
                              void* d_out, int out_size, void* d_ws, size_t ws_size,
                              hipStream_t stream) {
    const float* in_spike = (const float*)d_in[0];
    const float* in_cur   = (const float*)d_in[1];
    const float* v_in     = (const float*)d_in[2];
    const float* t_in     = (const float*)d_in[3];
    const float* w_i2h    = (const float*)d_in[4];
    const float* b_i2h    = (const float*)d_in[5];
    const float* w_h2h    = (const float*)d_in[6];
    const float* b_h2h    = (const float*)d_in[7];
    const float* w_h2o    = (const float*)d_in[8];
    const float* b_h2o    = (const float*)d_in[9];
    const float* syn_p    = (const float*)d_in[10];
    const float* vmin_p   = (const float*)d_in[11];
    const float* vmax_p   = (const float*)d_in[12];

    float* out0    = (float*)d_out;                     // output_spike [B,O]
    float* out1    = out0 + (size_t)B_SZ * O_SZ;        // output_potential [B,O]
    float* out_v   = out1 + (size_t)B_SZ * O_SZ;        // v [B,H]
    float* out_t   = out_v + (size_t)B_SZ * H_SZ;       // t [B]
    float* out_mdt = out_t + B_SZ;                      // min_dt [B]
    float* out_kf  = out_mdt + B_SZ;                    // k (float) [B]

    // workspace: eta f32 [B,H] | kidx int [B] | whhT f32 [H,H] | whoT f32 [H,O]
    float* eta  = (float*)d_ws;
    int*   kidx = (int*)(eta + (size_t)B_SZ * H_SZ);
    float* whhT = (float*)(kidx + B_SZ);
    float* whoT = whhT + (size_t)H_SZ * H_SZ;

    dim3 tb(32, 8);
    transpose_kernel<<<dim3(H_SZ / 32, H_SZ / 32), tb, 0, stream>>>(w_h2h, whhT,
                                                                    H_SZ, H_SZ);
    transpose_kernel<<<dim3(H_SZ / 32, O_SZ / 32), tb, 0, stream>>>(w_h2o, whoT,
                                                                    O_SZ, H_SZ);

    gemm_eta_f64acc_kernel<<<dim3(H_SZ / 64, B_SZ / 64), 256, 0, stream>>>(
        in_cur, w_i2h, b_i2h, b_h2h, eta);

    spike_min_kernel<<<B_SZ, 256, 0, stream>>>(v_in, in_spike, eta, t_in, syn_p,
                                               out_t, out_mdt, out_kf, kidx);

    update_v_kernel<<<(B_SZ * H_SZ / 4 + 255) / 256, 256, 0, stream>>>(
        v_in, in_spike, eta, out_mdt, kidx, whhT, syn_p, out_v);

    out_spike_kernel<<<(B_SZ * O_SZ / 4 + 255) / 256, 256, 0, stream>>>(kidx, whoT,
                                                                        out0);

    gemm_f32_clip_kernel<<<dim3(O_SZ / GT, B_SZ / GT), 256, 0, stream>>>(
        out_v, w_h2o, b_h2o, out1, H_SZ, vmin_p, vmax_p);
}

// Round 16
// 1123.515 us; speedup vs baseline: 1.1080x; 1.1080x over previous
//
#include <hip/hip_runtime.h>
#include <math.h>

#define B_SZ 8192
#define H_SZ 2048
#define I_SZ 1024
#define O_SZ 512

typedef double v4d __attribute__((ext_vector_type(4)));

// ======== f32 math mirroring numpy float32 semantics (r13-proven) ========

__device__ __forceinline__ float signf_(float x) {
    return (x > 0.f) ? 1.f : ((x < 0.f) ? -1.f : 0.f);
}

__device__ __forceinline__ float next_spike_f32(float v, float eta) {
#pragma clang fp contract(off)
    const float EPSf = 1e-6f;
    const float HEPSf = (float)(0.5 * 1e-6);
    const float T_INF = 10000.f;
    const float PI_F = (float)3.14159265358979323846;
    float ae = fabsf(eta) + EPSf;
    float se = (float)sqrt((double)ae);        // correctly-rounded f32 sqrt
    float s1 = signf_(v);
    float t1 = EPSf * s1;
    float va = v + t1;
    float vpe = v + EPSf;
    float s2 = signf_(vpe);
    float t2 = HEPSf * s2;
    float vs = va + t2;                        // ((v + e*s1) + he*s2)
    if (eta == 0.f) {
        if (v > 0.f) return 1.f / vs;
        return T_INF;
    }
    if (eta < 0.f) {
        if (v > se) {
            float r = se / vs;
            const float lo = (float)(-1.0 + 1e-6);
            const float hi = (float)(1.0 - 1e-6);
            r = fminf(fmaxf(r, lo), hi);
            float at = atanhf(r);              // ocml
            return at / se;
        }
        return T_INF;
    }
    float q = se / vs;
    float a = atanf(q);                        // ocml
    if (a < 0.f) a = a + PI_F;                 // np.mod(a, pi) for |a| < pi
    return a / se;
}

__device__ __forceinline__ float update_pot_f32(float v, float eta, float dt) {
#pragma clang fp contract(off)
    const float EPSf = 1e-6f;
    float ae = fabsf(eta) + EPSf;
    float se = (float)sqrt((double)ae);
    float r;
    if (eta == 0.f) {
        float t1 = dt * v;
        float den = 1.f - t1;
        r = v / den;
    } else if (eta < 0.f) {
        float x = se * dt;
        float th = tanhf(x);                   // ocml
        float t1 = se * th;
        float num = v - t1;
        float t2 = th * v;
        float t3 = t2 / se;
        float den = 1.f - t3;
        r = num / den;
    } else {
        float x = se * dt;
        float ta = tanf(x);                    // ocml
        float t1 = se * ta;
        float num = v + t1;
        float t2 = ta * v;
        float t3 = t2 / se;
        float den = 1.f - t3;
        r = num / den;
    }
    const float HI = (float)1e25;
    r = r < -HI ? -HI : (r > HI ? HI : r);     // NaN passes through, like np.clip
    return r;
}

// ---------------- transpose (32x32 LDS tiles) ----------------

__global__ __launch_bounds__(256) void transpose_kernel(const float* __restrict__ in,
                                                        float* __restrict__ out,
                                                        int R, int C) {
    __shared__ float tile[32][33];
    int bx = blockIdx.x * 32;
    int by = blockIdx.y * 32;
    int tx = threadIdx.x;
    int ty = threadIdx.y;
#pragma unroll
    for (int i = ty; i < 32; i += 8)
        tile[i][tx] = in[(size_t)(by + i) * C + bx + tx];
    __syncthreads();
#pragma unroll
    for (int i = ty; i < 32; i += 8)
        out[(size_t)(bx + i) * R + by + tx] = tile[tx][i];
}

// ---------------- eta GEMM: f64 MFMA (v_mfma_f64_16x16x4), f64-accurate dot ----------------
// Block 256 thr = 4 waves (2x2), block tile 128x128, per-wave 64x64 = 4x4 frags.
// A: lane = row + 16*k; B: lane = col + 16*k; D (STRIDED, K=4 family):
// row = 4*reg + lane>>4, col = lane&15.  eta32 = f32(f64 dot).

#define EBK 32

__global__ __launch_bounds__(256) void gemm_eta_mfma_f64(
    const float* __restrict__ A,    // [B,I]
    const float* __restrict__ Bm,   // [H,I]
    const float* __restrict__ b_i2h, const float* __restrict__ b_h2h,
    float* __restrict__ C) {
    __shared__ float As[128][36];
    __shared__ float Bs[128][36];
    const int tid = threadIdx.x;
    const int row0 = blockIdx.y * 128;   // batch rows
    const int col0 = blockIdx.x * 128;   // H cols
    const int wid = tid >> 6;            // wave 0..3
    const int lane = tid & 63;
    const int wrow = wid >> 1;           // 0..1
    const int wcol = wid & 1;            // 0..1
    const int lr = lane & 15;            // fragment row/col-in-16
    const int lk = lane >> 4;            // fragment k-in-4 / D row group

    v4d acc[4][4];
#pragma unroll
    for (int i = 0; i < 4; ++i)
#pragma unroll
        for (int j = 0; j < 4; ++j) acc[i][j] = (v4d){0.0, 0.0, 0.0, 0.0};

    const int srow = tid >> 3;           // 0..31
    const int sf4 = (tid & 7) << 2;      // 0,4,...,28

    for (int k0 = 0; k0 < I_SZ; k0 += EBK) {
#pragma unroll
        for (int p = 0; p < 4; ++p) {
            int r = p * 32 + srow;
            float4 a4 = *reinterpret_cast<const float4*>(
                A + (size_t)(row0 + r) * I_SZ + k0 + sf4);
            float4 b4 = *reinterpret_cast<const float4*>(
                Bm + (size_t)(col0 + r) * I_SZ + k0 + sf4);
            *reinterpret_cast<float4*>(&As[r][sf4]) = a4;
            *reinterpret_cast<float4*>(&Bs[r][sf4]) = b4;
        }
        __syncthreads();
#pragma unroll
        for (int ks = 0; ks < EBK / 4; ++ks) {   // ascending k, K=4 per mfma
            int kk = ks * 4 + lk;
            double a[4], b[4];
#pragma unroll
            for (int i = 0; i < 4; ++i)
                a[i] = (double)As[wrow * 64 + i * 16 + lr][kk];
#pragma unroll
            for (int j = 0; j < 4; ++j)
                b[j] = (double)Bs[wcol * 64 + j * 16 + lr][kk];
#pragma unroll
            for (int i = 0; i < 4; ++i)
#pragma unroll
                for (int j = 0; j < 4; ++j)
                    acc[i][j] = __builtin_amdgcn_mfma_f64_16x16x4f64(
                        a[i], b[j], acc[i][j], 0, 0, 0);
        }
        __syncthreads();
    }
    {
#pragma clang fp contract(off)
#pragma unroll
        for (int i = 0; i < 4; ++i) {
#pragma unroll
            for (int j = 0; j < 4; ++j) {
                int gcol = col0 + wcol * 64 + j * 16 + lr;
#pragma unroll
                for (int q = 0; q < 4; ++q) {
                    // STRIDED D layout: row = 4*reg + (lane>>4)
                    int grow = row0 + wrow * 64 + i * 16 + q * 4 + lk;
                    float m32 = (float)acc[i][j][q];    // f32 of f64-accurate dot
                    float s = b_h2h[gcol] + m32;        // (b_h2h + M)
                    s = s + b_i2h[gcol];                // + b_i2h
                    C[(size_t)grow * H_SZ + gcol] = s;
                }
            }
        }
    }
}

// ---------------- per-row next_spike + min/argmin (all f32) ----------------

__global__ __launch_bounds__(256) void spike_min_kernel(
    const float* __restrict__ v_in, const float* __restrict__ spike,
    const float* __restrict__ eta, const float* __restrict__ t_in,
    const float* __restrict__ syn_p,
    float* __restrict__ t_out, float* __restrict__ mdt_out,
    float* __restrict__ kf_out, int* __restrict__ kidx) {
#pragma clang fp contract(off)
    const int b = blockIdx.x;
    const int tid = threadIdx.x;
    const size_t base = (size_t)b * H_SZ;
    unsigned long long best = 0xFFFFFFFFFFFFFFFFull;
    for (int h = tid; h < H_SZ; h += 256) {
        float vv = v_in[base + h] + spike[base + h];
        float dt = next_spike_f32(vv, eta[base + h]);
        unsigned long long p =
            ((unsigned long long)__float_as_uint(dt) << 32) | (unsigned)h;
        best = (p < best) ? p : best;
    }
#pragma unroll
    for (int off = 1; off < 64; off <<= 1) {
        unsigned long long o = __shfl_xor(best, off);
        best = (o < best) ? o : best;
    }
    __shared__ unsigned long long s[4];
    if ((tid & 63) == 0) s[tid >> 6] = best;
    __syncthreads();
    if (tid == 0) {
        best = s[0];
#pragma unroll
        for (int w = 1; w < 4; ++w)
            if (s[w] < best) best = s[w];
        float mdt = __uint_as_float((unsigned)(best >> 32));
        int k = (int)(best & 0xFFFFFFFFu);
        mdt_out[b] = mdt;
        kf_out[b] = (float)k;
        kidx[b] = k;
        float tt = t_in[b] + mdt;   // np: (t + min_dt) + syn_delay
        tt = tt + (*syn_p);
        t_out[b] = tt;
    }
}

// ---------------- update potential (f32) + recurrent gather ----------------

__global__ __launch_bounds__(256) void update_v_kernel(
    const float* __restrict__ v_in, const float* __restrict__ spike,
    const float* __restrict__ eta, const float* __restrict__ mdt,
    const int* __restrict__ kidx, const float* __restrict__ whhT,
    const float* __restrict__ syn_p, float* __restrict__ v_out) {
#pragma clang fp contract(off)
    size_t i4 = ((size_t)blockIdx.x * 256 + threadIdx.x) * 4;
    if (i4 >= (size_t)B_SZ * H_SZ) return;
    int b = (int)(i4 >> 11);
    int h = (int)(i4 & (H_SZ - 1));
    float dt = mdt[b] + (*syn_p);   // one f32 rounding, matches (min_dt+syn)[:,None]
    int k = kidx[b];
    float4 v4 = *reinterpret_cast<const float4*>(v_in + i4);
    float4 s4 = *reinterpret_cast<const float4*>(spike + i4);
    float4 e4 = *reinterpret_cast<const float4*>(eta + i4);
    float4 w4 = *reinterpret_cast<const float4*>(whhT + (size_t)k * H_SZ + h);
    float4 r;
    r.x = update_pot_f32(v4.x + s4.x, e4.x, dt) + w4.x;
    r.y = update_pot_f32(v4.y + s4.y, e4.y, dt) + w4.y;
    r.z = update_pot_f32(v4.z + s4.z, e4.z, dt) + w4.z;
    r.w = update_pot_f32(v4.w + s4.w, e4.w, dt) + w4.w;
    *reinterpret_cast<float4*>(v_out + i4) = r;
}

// ---------------- output spike gather ----------------

__global__ __launch_bounds__(256) void out_spike_kernel(
    const int* __restrict__ kidx, const float* __restrict__ whoT,
    float* __restrict__ out0) {
    size_t i4 = ((size_t)blockIdx.x * 256 + threadIdx.x) * 4;
    if (i4 >= (size_t)B_SZ * O_SZ) return;
    int b = (int)(i4 >> 9);
    int o = (int)(i4 & (O_SZ - 1));
    int k = kidx[b];
    float4 w = *reinterpret_cast<const float4*>(whoT + (size_t)k * O_SZ + o);
    *reinterpret_cast<float4*>(out0 + i4) = w;
}

// ---------------- f32 tiled GEMM for output_potential (passed every round) ----------------

#define GT 128
#define GK 16

__global__ __launch_bounds__(256, 2) void gemm_f32_clip_kernel(
    const float* __restrict__ A, const float* __restrict__ Bm,
    const float* __restrict__ bias0, float* __restrict__ C,
    int K, const float* __restrict__ vminp, const float* __restrict__ vmaxp) {
    __shared__ float As[GK][GT + 4];
    __shared__ float Bs[GK][GT + 4];
    const int tid = threadIdx.x;
    const int row0 = blockIdx.y * GT;
    const int col0 = blockIdx.x * GT;
    const float vmin = *vminp, vmax = *vmaxp;
    const int lr = tid >> 2;
    const int lc = (tid & 3) << 2;
    const int ty = tid >> 4;
    const int tx = tid & 15;

    float acc[8][8];
#pragma unroll
    for (int i = 0; i < 8; ++i)
#pragma unroll
        for (int j = 0; j < 8; ++j) acc[i][j] = 0.f;

    for (int k0 = 0; k0 < K; k0 += GK) {
#pragma unroll
        for (int half = 0; half < 2; ++half) {
            int r = lr + half * 64;
            float4 a4 = *reinterpret_cast<const float4*>(A + (size_t)(row0 + r) * K + k0 + lc);
            a4.x = fminf(fmaxf(a4.x, vmin), vmax);
            a4.y = fminf(fmaxf(a4.y, vmin), vmax);
            a4.z = fminf(fmaxf(a4.z, vmin), vmax);
            a4.w = fminf(fmaxf(a4.w, vmin), vmax);
            As[lc + 0][r] = a4.x; As[lc + 1][r] = a4.y;
            As[lc + 2][r] = a4.z; As[lc + 3][r] = a4.w;
            float4 b4 = *reinterpret_cast<const float4*>(Bm + (size_t)(col0 + r) * K + k0 + lc);
            Bs[lc + 0][r] = b4.x; Bs[lc + 1][r] = b4.y;
            Bs[lc + 2][r] = b4.z; Bs[lc + 3][r] = b4.w;
        }
        __syncthreads();
#pragma unroll
        for (int kk = 0; kk < GK; ++kk) {
            float a[8], b[8];
#pragma unroll
            for (int i = 0; i < 8; ++i) a[i] = As[kk][ty * 8 + i];
#pragma unroll
            for (int j = 0; j < 8; ++j) b[j] = Bs[kk][tx * 8 + j];
#pragma unroll
            for (int i = 0; i < 8; ++i)
#pragma unroll
                for (int j = 0; j < 8; ++j) acc[i][j] = fmaf(a[i], b[j], acc[i][j]);
        }
        __syncthreads();
    }

    float bb[8];
#pragma unroll
    for (int j = 0; j < 8; ++j) bb[j] = bias0[col0 + tx * 8 + j];
#pragma unroll
    for (int i = 0; i < 8; ++i) {
        int row = row0 + ty * 8 + i;
#pragma unroll
        for (int j = 0; j < 8; j += 4) {
            float4 vstore;
            vstore.x = acc[i][j + 0] + bb[j + 0];
            vstore.y = acc[i][j + 1] + bb[j + 1];
            vstore.z = acc[i][j + 2] + bb[j + 2];
            vstore.w = acc[i][j + 3] + bb[j + 3];
            *reinterpret_cast<float4*>(C + (size_t)row * O_SZ + col0 + tx * 8 + j) = vstore;
        }
    }
}

// ---------------- launch ----------------

extern "C" void kernel_launch(void* const* d_in, const int* in_sizes, int n_in,
                              void* d_out, int out_size, void* d_ws, size_t ws_size,
                              hipStream_t stream) {
    const float* in_spike = (const float*)d_in[0];
    const float* in_cur   = (const float*)d_in[1];
    const float* v_in     = (const float*)d_in[2];
    const float* t_in     = (const float*)d_in[3];
    const float* w_i2h    = (const float*)d_in[4];
    const float* b_i2h    = (const float*)d_in[5];
    const float* w_h2h    = (const float*)d_in[6];
    const float* b_h2h    = (const float*)d_in[7];
    const float* w_h2o    = (const float*)d_in[8];
    const float* b_h2o    = (const float*)d_in[9];
    const float* syn_p    = (const float*)d_in[10];
    const float* vmin_p   = (const float*)d_in[11];
    const float* vmax_p   = (const float*)d_in[12];

    float* out0    = (float*)d_out;                     // output_spike [B,O]
    float* out1    = out0 + (size_t)B_SZ * O_SZ;        // output_potential [B,O]
    float* out_v   = out1 + (size_t)B_SZ * O_SZ;        // v [B,H]
    float* out_t   = out_v + (size_t)B_SZ * H_SZ;       // t [B]
    float* out_mdt = out_t + B_SZ;                      // min_dt [B]
    float* out_kf  = out_mdt + B_SZ;                    // k (float) [B]

    // workspace: eta f32 [B,H] | kidx int [B] | whhT f32 [H,H] | whoT f32 [H,O]
    float* eta  = (float*)d_ws;
    int*   kidx = (int*)(eta + (size_t)B_SZ * H_SZ);
    float* whhT = (float*)(kidx + B_SZ);
    float* whoT = whhT + (size_t)H_SZ * H_SZ;

    dim3 tb(32, 8);
    transpose_kernel<<<dim3(H_SZ / 32, H_SZ / 32), tb, 0, stream>>>(w_h2h, whhT,
                                                                    H_SZ, H_SZ);
    transpose_kernel<<<dim3(H_SZ / 32, O_SZ / 32), tb, 0, stream>>>(w_h2o, whoT,
                                                                    O_SZ, H_SZ);

    gemm_eta_mfma_f64<<<dim3(H_SZ / 128, B_SZ / 128), 256, 0, stream>>>(
        in_cur, w_i2h, b_i2h, b_h2h, eta);

    spike_min_kernel<<<B_SZ, 256, 0, stream>>>(v_in, in_spike, eta, t_in, syn_p,
                                               out_t, out_mdt, out_kf, kidx);

    update_v_kernel<<<(B_SZ * H_SZ / 4 + 255) / 256, 256, 0, stream>>>(
        v_in, in_spike, eta, out_mdt, kidx, whhT, syn_p, out_v);

    out_spike_kernel<<<(B_SZ * O_SZ / 4 + 255) / 256, 256, 0, stream>>>(kidx, whoT,
                                                                        out0);

    gemm_f32_clip_kernel<<<dim3(O_SZ / GT, B_SZ / GT), 256, 0, stream>>>(
        out_v, w_h2o, b_h2o, out1, H_SZ, vmin_p, vmax_p);
}